// Round 1
// baseline (1296.307 us; speedup 1.0000x reference)
//
#include <hip/hip_runtime.h>

#define NN 4096
#define DD 128
#define REGC 0.05f
#define EPSC 1e-8f
#define NSINK 32

typedef _Float16 f16x8 __attribute__((ext_vector_type(8)));
typedef float f32x4 __attribute__((ext_vector_type(4)));
typedef short s16x8 __attribute__((ext_vector_type(8)));

__device__ __forceinline__ float wave_reduce_sum(float s) {
#pragma unroll
  for (int m = 32; m >= 1; m >>= 1) s += __shfl_xor(s, m, 64);
  return s;
}

__device__ __forceinline__ short f32_to_bf16(float f) {
  union { float f; unsigned u; } x; x.f = f;
  unsigned r = (x.u + 0x7FFFu + ((x.u >> 16) & 1u)) >> 16;
  return (short)r;
}

// grid 12288 blocks (zi*4096 + row), block 128: row norms, bf16 convert, u=1 init
__global__ __launch_bounds__(128) void prep_kernel(const float* __restrict__ z0, const float* __restrict__ z1,
                                                   const float* __restrict__ z2, short* __restrict__ zb,
                                                   float* __restrict__ sq, float* __restrict__ u) {
  int row = blockIdx.x;
  int zi = row >> 12;
  const float* z = (zi == 0) ? z0 : ((zi == 1) ? z1 : z2);
  int r = row & (NN - 1);
  float val = z[r * DD + threadIdx.x];
  zb[row * DD + threadIdx.x] = f32_to_bf16(val);
  float s = wave_reduce_sum(val * val);
  __shared__ float red[2];
  if ((threadIdx.x & 63) == 0) red[threadIdx.x >> 6] = s;
  __syncthreads();
  if (threadIdx.x == 0) { sq[row] = red[0] + red[1]; u[row] = 1.0f; }
}

// grid dim3(64, 64, 3), block 256: K[p] = fp16(exp(-clip(xsq+ysq-2 x.y, 0)/reg))
__global__ __launch_bounds__(256) void kbuild_kernel(const short* __restrict__ zb, const float* __restrict__ sq,
                                                     _Float16* __restrict__ K) {
  int p = blockIdx.z;
  int ai = (p == 2) ? 1 : 0;            // pairs (0,1),(0,2),(1,2)
  int bi = (p == 0) ? 1 : 2;
  const short* xb = zb + ai * NN * DD;
  const short* yb = zb + bi * NN * DD;
  const float* sqx = sq + ai * NN;
  const float* sqy = sq + bi * NN;
  _Float16* Kp = K + (size_t)p * NN * NN;
  int r0 = blockIdx.y * 64;
  int c0 = blockIdx.x * 64;
  int w = threadIdx.x >> 6;
  int lane = threadIdx.x & 63;
  int lrow = lane & 15;
  int lk = lane >> 4;                   // 0..3 (k-group for A/B, row-group for D)
  const short* aptr = xb + (r0 + w * 16 + lrow) * DD + lk * 8;
  f32x4 acc0 = {0.f, 0.f, 0.f, 0.f};
  f32x4 acc1 = acc0, acc2 = acc0, acc3 = acc0;
#pragma unroll
  for (int kk = 0; kk < DD; kk += 32) {
    s16x8 a = *(const s16x8*)(aptr + kk);
    const short* bbase = yb + (c0 + lrow) * DD + lk * 8 + kk;
    acc0 = __builtin_amdgcn_mfma_f32_16x16x32_bf16(a, *(const s16x8*)(bbase + 0 * 16 * DD), acc0, 0, 0, 0);
    acc1 = __builtin_amdgcn_mfma_f32_16x16x32_bf16(a, *(const s16x8*)(bbase + 1 * 16 * DD), acc1, 0, 0, 0);
    acc2 = __builtin_amdgcn_mfma_f32_16x16x32_bf16(a, *(const s16x8*)(bbase + 2 * 16 * DD), acc2, 0, 0, 0);
    acc3 = __builtin_amdgcn_mfma_f32_16x16x32_bf16(a, *(const s16x8*)(bbase + 3 * 16 * DD), acc3, 0, 0, 0);
  }
  int drow0 = r0 + w * 16 + lk * 4;
#pragma unroll
  for (int ct = 0; ct < 4; ct++) {
    f32x4 acc = (ct == 0) ? acc0 : (ct == 1) ? acc1 : (ct == 2) ? acc2 : acc3;
    int col = c0 + ct * 16 + lrow;
    float sy = sqy[col];
#pragma unroll
    for (int r = 0; r < 4; r++) {
      int row = drow0 + r;
      float Cv = fmaxf(sqx[row] + sy - 2.0f * acc[r], 0.0f);
      Kp[(size_t)row * NN + col] = (_Float16)__expf(Cv * (-1.0f / REGC));
    }
  }
}

// grid dim3(8, 32, 3), block 256: t[p][j] += sum_i K[p][i][j] * u[p][i]  (t pre-zeroed)
__global__ __launch_bounds__(256) void sink_t_kernel(const _Float16* __restrict__ K, const float* __restrict__ u,
                                                     float* __restrict__ t) {
  int p = blockIdx.z;
  int strip = blockIdx.x;               // 512-col strip
  int chunk = blockIdx.y;               // 128-row chunk
  int w = threadIdx.x >> 6, lane = threadIdx.x & 63;
  const _Float16* Kp = K + (size_t)p * NN * NN;
  const float* up = u + p * NN;
  int c0 = strip * 512 + lane * 8;
  float a0 = 0, a1 = 0, a2 = 0, a3 = 0, a4 = 0, a5 = 0, a6 = 0, a7 = 0;
  int rbase = chunk * 128;
  for (int r = w; r < 128; r += 4) {
    int row = rbase + r;
    float ur = up[row];
    f16x8 k8 = *(const f16x8*)(Kp + (size_t)row * NN + c0);
    a0 += (float)k8[0] * ur; a1 += (float)k8[1] * ur;
    a2 += (float)k8[2] * ur; a3 += (float)k8[3] * ur;
    a4 += (float)k8[4] * ur; a5 += (float)k8[5] * ur;
    a6 += (float)k8[6] * ur; a7 += (float)k8[7] * ur;
  }
  __shared__ float red[4][512];
  int cb = lane * 8;
  red[w][cb + 0] = a0; red[w][cb + 1] = a1; red[w][cb + 2] = a2; red[w][cb + 3] = a3;
  red[w][cb + 4] = a4; red[w][cb + 5] = a5; red[w][cb + 6] = a6; red[w][cb + 7] = a7;
  __syncthreads();
  for (int c = threadIdx.x; c < 512; c += 256) {
    float s = red[0][c] + red[1][c] + red[2][c] + red[3][c];
    atomicAdd(&t[p * NN + strip * 512 + c], s);
  }
}

// grid 768 (p*256 + rowblock), block 256: v = nu/(t+eps) in LDS; u = mu/(K v + eps); zero tother
__global__ __launch_bounds__(256) void sink_u_kernel(const _Float16* __restrict__ K, const float* __restrict__ tcur,
                                                     float* __restrict__ u, float* __restrict__ tother) {
  int bid = blockIdx.x;
  int p = bid >> 8;
  int rb = bid & 255;
  __shared__ float vlds[NN];
  const float* tp = tcur + p * NN;
  for (int j = threadIdx.x; j < NN; j += 256) vlds[j] = (1.0f / NN) / (tp[j] + EPSC);
  if (threadIdx.x < 16) tother[bid * 16 + threadIdx.x] = 0.0f;
  __syncthreads();
  int w = threadIdx.x >> 6, lane = threadIdx.x & 63;
  const _Float16* Kp = K + (size_t)p * NN * NN;
#pragma unroll 1
  for (int rr = 0; rr < 4; rr++) {
    int row = rb * 16 + w * 4 + rr;
    float a0 = 0, a1 = 0, a2 = 0, a3 = 0, a4 = 0, a5 = 0, a6 = 0, a7 = 0;
    for (int base = 0; base < NN; base += 512) {
      f16x8 k8 = *(const f16x8*)(Kp + (size_t)row * NN + base + lane * 8);
      f32x4 va = *(const f32x4*)&vlds[base + lane * 8];
      f32x4 vb = *(const f32x4*)&vlds[base + lane * 8 + 4];
      a0 += (float)k8[0] * va[0]; a1 += (float)k8[1] * va[1];
      a2 += (float)k8[2] * va[2]; a3 += (float)k8[3] * va[3];
      a4 += (float)k8[4] * vb[0]; a5 += (float)k8[5] * vb[1];
      a6 += (float)k8[6] * vb[2]; a7 += (float)k8[7] * vb[3];
    }
    float racc = ((a0 + a1) + (a2 + a3)) + ((a4 + a5) + (a6 + a7));
    racc = wave_reduce_sum(racc);
    if (lane == 0) u[p * NN + row] = (1.0f / NN) / (racc + EPSC);
  }
}

// grid 768, block 256: loss += u_i K_ij v_j C_ij, C = -reg*ln(K)
__global__ __launch_bounds__(256) void loss_kernel(const _Float16* __restrict__ K, const float* __restrict__ tcur,
                                                   const float* __restrict__ u, float* __restrict__ out) {
  int bid = blockIdx.x;
  int p = bid >> 8;
  int rb = bid & 255;
  __shared__ float vlds[NN];
  const float* tp = tcur + p * NN;
  for (int j = threadIdx.x; j < NN; j += 256) vlds[j] = (1.0f / NN) / (tp[j] + EPSC);
  __syncthreads();
  int w = threadIdx.x >> 6, lane = threadIdx.x & 63;
  const _Float16* Kp = K + (size_t)p * NN * NN;
  const float* up = u + p * NN;
  float lt = 0.0f;
#pragma unroll 1
  for (int rr = 0; rr < 4; rr++) {
    int row = rb * 16 + w * 4 + rr;
    float ur = up[row];
    float racc = 0.0f;
    for (int base = 0; base < NN; base += 512) {
      f16x8 k8 = *(const f16x8*)(Kp + (size_t)row * NN + base + lane * 8);
      f32x4 va = *(const f32x4*)&vlds[base + lane * 8];
      f32x4 vb = *(const f32x4*)&vlds[base + lane * 8 + 4];
#pragma unroll
      for (int j = 0; j < 8; j++) {
        float kf = (float)k8[j];
        float cf = -REGC * __logf(kf);
        float vj = (j < 4) ? va[j] : vb[j - 4];
        racc += kf * vj * cf;
      }
    }
    lt += ur * racc;
  }
  lt = wave_reduce_sum(lt);
  __shared__ float red[4];
  if (lane == 0) red[w] = lt;
  __syncthreads();
  if (threadIdx.x == 0) atomicAdd(out, (red[0] + red[1] + red[2] + red[3]) * (1.0f / 3.0f));
}

extern "C" void kernel_launch(void* const* d_in, const int* in_sizes, int n_in,
                              void* d_out, int out_size, void* d_ws, size_t ws_size,
                              hipStream_t stream) {
  const float* z0 = (const float*)d_in[0];
  const float* z1 = (const float*)d_in[1];
  const float* z2 = (const float*)d_in[2];
  float* out = (float*)d_out;
  char* ws = (char*)d_ws;

  const size_t K_BYTES = (size_t)3 * NN * NN * 2;        // 100663296
  _Float16* K = (_Float16*)ws;
  short* zb = (short*)(ws + K_BYTES);                    // 3*4096*128*2 = 3145728
  float* sq = (float*)(ws + K_BYTES + 3145728);          // 49152
  float* u = (float*)(ws + K_BYTES + 3145728 + 49152);   // 49152
  float* t0 = (float*)(ws + K_BYTES + 3145728 + 2 * 49152);
  float* t1 = (float*)(ws + K_BYTES + 3145728 + 3 * 49152);

  hipMemsetAsync(d_out, 0, sizeof(float), stream);
  hipMemsetAsync(t0, 0, 2 * 3 * NN * sizeof(float), stream);  // t0 and t1 contiguous

  prep_kernel<<<3 * NN, 128, 0, stream>>>(z0, z1, z2, zb, sq, u);
  kbuild_kernel<<<dim3(64, 64, 3), 256, 0, stream>>>(zb, sq, K);

  float* tc = t0;
  float* to = t1;
  for (int it = 0; it < NSINK; it++) {
    sink_t_kernel<<<dim3(8, 32, 3), 256, 0, stream>>>(K, u, tc);
    sink_u_kernel<<<768, 256, 0, stream>>>(K, tc, u, to);
    float* tmp = tc; tc = to; to = tmp;
  }
  // after the swap, `to` is the t-buffer the final v was computed from
  loss_kernel<<<768, 256, 0, stream>>>(K, to, u, out);
}

// Round 2
// 714.543 us; speedup vs baseline: 1.8142x; 1.8142x over previous
//
#include <hip/hip_runtime.h>

#define NN 4096
#define DD 128
#define REGC 0.05f
#define EPSC 1e-8f
#define NSINK 20

typedef float f32x4 __attribute__((ext_vector_type(4)));
typedef float f32x2 __attribute__((ext_vector_type(2)));
typedef short s16x8 __attribute__((ext_vector_type(8)));

__device__ __forceinline__ float wave_reduce_sum(float s) {
#pragma unroll
  for (int m = 32; m >= 1; m >>= 1) s += __shfl_xor(s, m, 64);
  return s;
}

__device__ __forceinline__ short f32_to_bf16(float f) {
  union { float f; unsigned u; } x; x.f = f;
  unsigned r = (x.u + 0x7FFFu + ((x.u >> 16) & 1u)) >> 16;
  return (short)r;
}

// decode 8 packed fp8 (e4m3) from a uint2 into 8 floats
__device__ __forceinline__ void fp8x8_decode(uint2 k, float* o) {
  f32x2 p0 = __builtin_amdgcn_cvt_pk_f32_fp8((int)k.x, false);
  f32x2 p1 = __builtin_amdgcn_cvt_pk_f32_fp8((int)k.x, true);
  f32x2 p2 = __builtin_amdgcn_cvt_pk_f32_fp8((int)k.y, false);
  f32x2 p3 = __builtin_amdgcn_cvt_pk_f32_fp8((int)k.y, true);
  o[0] = p0[0]; o[1] = p0[1]; o[2] = p1[0]; o[3] = p1[1];
  o[4] = p2[0]; o[5] = p2[1]; o[6] = p3[0]; o[7] = p3[1];
}

// grid 12288 blocks (zi*4096 + row), block 128: row norms, bf16 convert, u=1 init
__global__ __launch_bounds__(128) void prep_kernel(const float* __restrict__ z0, const float* __restrict__ z1,
                                                   const float* __restrict__ z2, short* __restrict__ zb,
                                                   float* __restrict__ sq, float* __restrict__ u) {
  int row = blockIdx.x;
  int zi = row >> 12;
  const float* z = (zi == 0) ? z0 : ((zi == 1) ? z1 : z2);
  int r = row & (NN - 1);
  float val = z[r * DD + threadIdx.x];
  zb[row * DD + threadIdx.x] = f32_to_bf16(val);
  float s = wave_reduce_sum(val * val);
  __shared__ float red[2];
  if ((threadIdx.x & 63) == 0) red[threadIdx.x >> 6] = s;
  __syncthreads();
  if (threadIdx.x == 0) { sq[row] = red[0] + red[1]; u[row] = 1.0f; }
}

// grid dim3(64, 64, 3), block 256: K[p] = fp8(exp(-clip(xsq+ysq-2 x.y, 0)/reg))
__global__ __launch_bounds__(256) void kbuild_kernel(const short* __restrict__ zb, const float* __restrict__ sq,
                                                     unsigned char* __restrict__ K) {
  int p = blockIdx.z;
  int ai = (p == 2) ? 1 : 0;            // pairs (0,1),(0,2),(1,2)
  int bi = (p == 0) ? 1 : 2;
  const short* xb = zb + ai * NN * DD;
  const short* yb = zb + bi * NN * DD;
  const float* sqx = sq + ai * NN;
  const float* sqy = sq + bi * NN;
  unsigned char* Kp = K + (size_t)p * NN * NN;
  int r0 = blockIdx.y * 64;
  int c0 = blockIdx.x * 64;
  int w = threadIdx.x >> 6;
  int lane = threadIdx.x & 63;
  int lrow = lane & 15;
  int lk = lane >> 4;                   // 0..3 (k-group for A/B, row-group for D)
  const short* aptr = xb + (r0 + w * 16 + lrow) * DD + lk * 8;
  f32x4 acc0 = {0.f, 0.f, 0.f, 0.f};
  f32x4 acc1 = acc0, acc2 = acc0, acc3 = acc0;
#pragma unroll
  for (int kk = 0; kk < DD; kk += 32) {
    s16x8 a = *(const s16x8*)(aptr + kk);
    const short* bbase = yb + (c0 + lrow) * DD + lk * 8 + kk;
    acc0 = __builtin_amdgcn_mfma_f32_16x16x32_bf16(a, *(const s16x8*)(bbase + 0 * 16 * DD), acc0, 0, 0, 0);
    acc1 = __builtin_amdgcn_mfma_f32_16x16x32_bf16(a, *(const s16x8*)(bbase + 1 * 16 * DD), acc1, 0, 0, 0);
    acc2 = __builtin_amdgcn_mfma_f32_16x16x32_bf16(a, *(const s16x8*)(bbase + 2 * 16 * DD), acc2, 0, 0, 0);
    acc3 = __builtin_amdgcn_mfma_f32_16x16x32_bf16(a, *(const s16x8*)(bbase + 3 * 16 * DD), acc3, 0, 0, 0);
  }
  int drow0 = r0 + w * 16 + lk * 4;
#pragma unroll
  for (int ct = 0; ct < 4; ct++) {
    f32x4 acc = (ct == 0) ? acc0 : (ct == 1) ? acc1 : (ct == 2) ? acc2 : acc3;
    int col = c0 + ct * 16 + lrow;
    float sy = sqy[col];
#pragma unroll
    for (int r = 0; r < 4; r++) {
      int row = drow0 + r;
      float Cv = fmaxf(sqx[row] + sy - 2.0f * acc[r], 0.0f);
      float kf = __expf(Cv * (-1.0f / REGC));
      int pk = __builtin_amdgcn_cvt_pk_fp8_f32(kf, kf, 0, false);
      Kp[(size_t)row * NN + col] = (unsigned char)(pk & 0xFF);
    }
  }
}

// grid dim3(8, 32, 3), block 256: t[p][j] += sum_i K[p][i][j] * u[p][i]  (t pre-zeroed)
__global__ __launch_bounds__(256) void sink_t_kernel(const unsigned char* __restrict__ K, const float* __restrict__ u,
                                                     float* __restrict__ t) {
  int p = blockIdx.z;
  int strip = blockIdx.x;               // 512-col strip
  int chunk = blockIdx.y;               // 128-row chunk
  int w = threadIdx.x >> 6, lane = threadIdx.x & 63;
  const unsigned char* Kp = K + (size_t)p * NN * NN;
  const float* up = u + p * NN;
  int c0 = strip * 512 + lane * 8;
  float a0 = 0, a1 = 0, a2 = 0, a3 = 0, a4 = 0, a5 = 0, a6 = 0, a7 = 0;
  int rbase = chunk * 128;
  for (int r = w; r < 128; r += 4) {
    int row = rbase + r;
    float ur = up[row];
    uint2 k8 = *(const uint2*)(Kp + (size_t)row * NN + c0);
    float kd[8];
    fp8x8_decode(k8, kd);
    a0 += kd[0] * ur; a1 += kd[1] * ur; a2 += kd[2] * ur; a3 += kd[3] * ur;
    a4 += kd[4] * ur; a5 += kd[5] * ur; a6 += kd[6] * ur; a7 += kd[7] * ur;
  }
  __shared__ float red[4][512];
  int cb = lane * 8;
  red[w][cb + 0] = a0; red[w][cb + 1] = a1; red[w][cb + 2] = a2; red[w][cb + 3] = a3;
  red[w][cb + 4] = a4; red[w][cb + 5] = a5; red[w][cb + 6] = a6; red[w][cb + 7] = a7;
  __syncthreads();
  for (int c = threadIdx.x; c < 512; c += 256) {
    float s = red[0][c] + red[1][c] + red[2][c] + red[3][c];
    atomicAdd(&t[p * NN + strip * 512 + c], s);
  }
}

// grid 768 (p*256 + rowblock), block 256: v = nu/(t+eps) in LDS; u = mu/(K v + eps); zero tother
__global__ __launch_bounds__(256) void sink_u_kernel(const unsigned char* __restrict__ K, const float* __restrict__ tcur,
                                                     float* __restrict__ u, float* __restrict__ tother) {
  int bid = blockIdx.x;
  int p = bid >> 8;
  int rb = bid & 255;
  __shared__ float vlds[NN];
  const float* tp = tcur + p * NN;
  for (int j = threadIdx.x; j < NN; j += 256) vlds[j] = (1.0f / NN) / (tp[j] + EPSC);
  if (threadIdx.x < 16) tother[bid * 16 + threadIdx.x] = 0.0f;
  __syncthreads();
  int w = threadIdx.x >> 6, lane = threadIdx.x & 63;
  const unsigned char* Kp = K + (size_t)p * NN * NN;
#pragma unroll 1
  for (int rr = 0; rr < 4; rr++) {
    int row = rb * 16 + w * 4 + rr;
    float a0 = 0, a1 = 0, a2 = 0, a3 = 0, a4 = 0, a5 = 0, a6 = 0, a7 = 0;
    for (int base = 0; base < NN; base += 512) {
      uint2 k8 = *(const uint2*)(Kp + (size_t)row * NN + base + lane * 8);
      float kd[8];
      fp8x8_decode(k8, kd);
      f32x4 va = *(const f32x4*)&vlds[base + lane * 8];
      f32x4 vb = *(const f32x4*)&vlds[base + lane * 8 + 4];
      a0 += kd[0] * va[0]; a1 += kd[1] * va[1];
      a2 += kd[2] * va[2]; a3 += kd[3] * va[3];
      a4 += kd[4] * vb[0]; a5 += kd[5] * vb[1];
      a6 += kd[6] * vb[2]; a7 += kd[7] * vb[3];
    }
    float racc = ((a0 + a1) + (a2 + a3)) + ((a4 + a5) + (a6 + a7));
    racc = wave_reduce_sum(racc);
    if (lane == 0) u[p * NN + row] = (1.0f / NN) / (racc + EPSC);
  }
}

// grid 768, block 256: loss += u_i K_ij v_j C_ij, C = -reg*ln(K)
__global__ __launch_bounds__(256) void loss_kernel(const unsigned char* __restrict__ K, const float* __restrict__ tcur,
                                                   const float* __restrict__ u, float* __restrict__ out) {
  int bid = blockIdx.x;
  int p = bid >> 8;
  int rb = bid & 255;
  __shared__ float vlds[NN];
  const float* tp = tcur + p * NN;
  for (int j = threadIdx.x; j < NN; j += 256) vlds[j] = (1.0f / NN) / (tp[j] + EPSC);
  __syncthreads();
  int w = threadIdx.x >> 6, lane = threadIdx.x & 63;
  const unsigned char* Kp = K + (size_t)p * NN * NN;
  const float* up = u + p * NN;
  float lt = 0.0f;
#pragma unroll 1
  for (int rr = 0; rr < 4; rr++) {
    int row = rb * 16 + w * 4 + rr;
    float ur = up[row];
    float racc = 0.0f;
    for (int base = 0; base < NN; base += 512) {
      uint2 k8 = *(const uint2*)(Kp + (size_t)row * NN + base + lane * 8);
      float kd[8];
      fp8x8_decode(k8, kd);
      f32x4 va = *(const f32x4*)&vlds[base + lane * 8];
      f32x4 vb = *(const f32x4*)&vlds[base + lane * 8 + 4];
#pragma unroll
      for (int j = 0; j < 8; j++) {
        float kf = kd[j];
        float cf = -REGC * __logf(kf);
        float vj = (j < 4) ? va[j] : vb[j - 4];
        racc += kf * vj * cf;
      }
    }
    lt += ur * racc;
  }
  lt = wave_reduce_sum(lt);
  __shared__ float red[4];
  if (lane == 0) red[w] = lt;
  __syncthreads();
  if (threadIdx.x == 0) atomicAdd(out, (red[0] + red[1] + red[2] + red[3]) * (1.0f / 3.0f));
}

extern "C" void kernel_launch(void* const* d_in, const int* in_sizes, int n_in,
                              void* d_out, int out_size, void* d_ws, size_t ws_size,
                              hipStream_t stream) {
  const float* z0 = (const float*)d_in[0];
  const float* z1 = (const float*)d_in[1];
  const float* z2 = (const float*)d_in[2];
  float* out = (float*)d_out;
  char* ws = (char*)d_ws;

  const size_t K_BYTES = (size_t)3 * NN * NN;            // 50331648 (fp8)
  unsigned char* K = (unsigned char*)ws;
  short* zb = (short*)(ws + K_BYTES);                    // 3*4096*128*2 = 3145728
  float* sq = (float*)(ws + K_BYTES + 3145728);          // 49152
  float* u = (float*)(ws + K_BYTES + 3145728 + 49152);   // 49152
  float* t0 = (float*)(ws + K_BYTES + 3145728 + 2 * 49152);
  float* t1 = (float*)(ws + K_BYTES + 3145728 + 3 * 49152);

  hipMemsetAsync(d_out, 0, sizeof(float), stream);
  hipMemsetAsync(t0, 0, 2 * 3 * NN * sizeof(float), stream);  // t0 and t1 contiguous

  prep_kernel<<<3 * NN, 128, 0, stream>>>(z0, z1, z2, zb, sq, u);
  kbuild_kernel<<<dim3(64, 64, 3), 256, 0, stream>>>(zb, sq, K);

  float* tc = t0;
  float* to = t1;
  for (int it = 0; it < NSINK; it++) {
    sink_t_kernel<<<dim3(8, 32, 3), 256, 0, stream>>>(K, u, tc);
    sink_u_kernel<<<768, 256, 0, stream>>>(K, tc, u, to);
    float* tmp = tc; tc = to; to = tmp;
  }
  // after the swap, `to` is the t-buffer the final v was computed from
  loss_kernel<<<768, 256, 0, stream>>>(K, to, u, out);
}